// Round 1
// baseline (259.261 us; speedup 1.0000x reference)
//
#include <hip/hip_runtime.h>

#define N_RES 2048
#define BATCH 16
#define LMAX  13
#define NSLOT 14          // LMAX atm slots + 1 amn slot
#define VPAD  68          // v-row pad (floats): 16B-aligned rows, bank stride 4
#define DV    64

__device__ __constant__ int RES_LEN_D[20] = {3,4,5,5,6,6,6,7,7,7,7,7,8,8,8,9,10,10,11,13};

__global__ __launch_bounds__(256, 3)
void posmix_kernel(const float* __restrict__ pos_atm,
                   const float* __restrict__ pos_amn,
                   const float* __restrict__ W_amn,
                   const float* __restrict__ W_atm,
                   const int*   __restrict__ seq,
                   float* __restrict__ out_atm,
                   float* __restrict__ out_amn,
                   int atoms)
{
  const int i   = blockIdx.x;
  const int tid = threadIdx.x;
  const int t   = seq[i];
  const int L   = RES_LEN_D[t];

  __shared__ float w_lds[NSLOT * LMAX * VPAD];   // [slot m][l][v(+pad)]
  __shared__ float diff_lds[BATCH * LMAX * 4];   // [b][l][xyz0]

  // ---- start_i = sum of lens of residues < i (reduction in aliased LDS) ----
  int* red = (int*)w_lds;
  {
    int s = 0;
    int base = tid * 8;
    #pragma unroll
    for (int k = 0; k < 8; ++k) {
      int r = base + k;
      if (r < i) s += RES_LEN_D[seq[r]];
    }
    red[tid] = s;
  }
  __syncthreads();
  #pragma unroll
  for (int off = 128; off > 0; off >>= 1) {
    if (tid < off) red[tid] += red[tid + off];
    __syncthreads();
  }
  const int start = red[0];
  __syncthreads();   // done with red alias before W staging overwrites it

  // ---- stage diffs: diff[b][l][.] = pos_atm[b, start+l] - pos_amn[b, i] ----
  if (tid < BATCH * LMAX) {
    int b = tid / LMAX;
    int l = tid - b * LMAX;
    float dx = 0.f, dy = 0.f, dz = 0.f;
    if (l < L) {
      const float* pa = pos_atm + ((size_t)b * atoms + (size_t)(start + l)) * 3;
      const float* pm = pos_amn + ((size_t)b * N_RES + i) * 3;
      dx = pa[0] - pm[0];
      dy = pa[1] - pm[1];
      dz = pa[2] - pm[2];
    }
    *(float4*)(diff_lds + tid * 4) = make_float4(dx, dy, dz, 0.f);
  }

  // ---- stage W_atm[t] transposed (m,v,l)->[m][l][v], m < L ----
  {
    const float* Wt = W_atm + (size_t)t * (LMAX * DV * LMAX);
    const int total = L * DV * LMAX;
    for (int g = tid; g < total; g += 256) {
      int m = g / (DV * LMAX);
      int r = g - m * (DV * LMAX);
      int v = r / LMAX;
      int l = r - v * LMAX;
      w_lds[(m * LMAX + l) * VPAD + v] = Wt[g];
    }
    // ---- stage W_amn[t] (o,l)->[slot L][l][o] ----
    const float* Wa = W_amn + (size_t)t * (DV * LMAX);
    for (int g = tid; g < DV * LMAX; g += 256) {
      int o = g / LMAX;
      int l = g - o * LMAX;
      w_lds[(L * LMAX + l) * VPAD + o] = Wa[g];
    }
  }
  __syncthreads();

  // ---- compute: task = (bp: 8 batch-pairs) x (m: L+1 slots) x (vo: 8 v-octets) ----
  const int Lp1 = L + 1;
  const int ntasks = 64 * Lp1;

  for (int task = tid; task < ntasks; task += 256) {
    int vo   = task & 7;
    int rest = task >> 3;
    int bp   = rest / Lp1;
    int m    = rest - bp * Lp1;

    float acc0[24], acc1[24];
    #pragma unroll
    for (int k = 0; k < 24; ++k) { acc0[k] = 0.f; acc1[k] = 0.f; }

    const float* wr = w_lds + (m * LMAX) * VPAD + vo * 8;
    const float* dr = diff_lds + (bp * 2) * (LMAX * 4);

    for (int l = 0; l < L; ++l) {
      float4 w0 = *(const float4*)(wr + l * VPAD);
      float4 w1 = *(const float4*)(wr + l * VPAD + 4);
      float4 d0 = *(const float4*)(dr + l * 4);
      float4 d1 = *(const float4*)(dr + (LMAX * 4) + l * 4);
      float wv[8] = {w0.x, w0.y, w0.z, w0.w, w1.x, w1.y, w1.z, w1.w};
      #pragma unroll
      for (int k = 0; k < 8; ++k) {
        acc0[k*3+0] += wv[k] * d0.x;
        acc0[k*3+1] += wv[k] * d0.y;
        acc0[k*3+2] += wv[k] * d0.z;
        acc1[k*3+0] += wv[k] * d1.x;
        acc1[k*3+1] += wv[k] * d1.y;
        acc1[k*3+2] += wv[k] * d1.z;
      }
    }

    const int b0 = bp * 2, b1 = b0 + 1;
    float* dst0;
    float* dst1;
    if (m < L) {
      size_t a = (size_t)(start + m);
      dst0 = out_atm + ((size_t)b0 * atoms + a) * (DV * 3) + vo * 24;
      dst1 = out_atm + ((size_t)b1 * atoms + a) * (DV * 3) + vo * 24;
    } else {
      dst0 = out_amn + ((size_t)b0 * N_RES + i) * (DV * 3) + vo * 24;
      dst1 = out_amn + ((size_t)b1 * N_RES + i) * (DV * 3) + vo * 24;
    }
    #pragma unroll
    for (int q = 0; q < 6; ++q) {
      ((float4*)dst0)[q] = make_float4(acc0[q*4+0], acc0[q*4+1], acc0[q*4+2], acc0[q*4+3]);
      ((float4*)dst1)[q] = make_float4(acc1[q*4+0], acc1[q*4+1], acc1[q*4+2], acc1[q*4+3]);
    }
  }
}

extern "C" void kernel_launch(void* const* d_in, const int* in_sizes, int n_in,
                              void* d_out, int out_size, void* d_ws, size_t ws_size,
                              hipStream_t stream) {
  const float* pos_atm = (const float*)d_in[0];
  const float* pos_amn = (const float*)d_in[1];
  const float* W_amn   = (const float*)d_in[2];
  const float* W_atm   = (const float*)d_in[3];
  const int*   seq     = (const int*)d_in[4];

  const int atoms = in_sizes[0] / (BATCH * 3);   // 15036
  float* out_atm = (float*)d_out;
  float* out_amn = out_atm + (size_t)BATCH * atoms * DV * 3;

  posmix_kernel<<<N_RES, 256, 0, stream>>>(pos_atm, pos_amn, W_amn, W_atm, seq,
                                           out_atm, out_amn, atoms);
}

// Round 2
// 245.568 us; speedup vs baseline: 1.0558x; 1.0558x over previous
//
#include <hip/hip_runtime.h>

#define N_RES 2048
#define BATCH 16
#define LMAX  13
#define NSLOT 14          // LMAX atm slots + 1 amn slot
#define DV    64
#define DPAD  7           // diff row: x y z x y z pad

__device__ __constant__ int RES_LEN_D[20] = {3,4,5,5,6,6,6,7,7,7,7,7,8,8,8,9,10,10,11,13};

__global__ __launch_bounds__(256, 3)
void posmix_kernel(const float* __restrict__ pos_atm,
                   const float* __restrict__ pos_amn,
                   const float* __restrict__ W_amn,
                   const float* __restrict__ W_atm,
                   const int*   __restrict__ seq,
                   float* __restrict__ out_atm,
                   float* __restrict__ out_amn,
                   int atoms)
{
  const int i   = blockIdx.x;
  const int tid = threadIdx.x;
  const int t   = seq[i];
  const int L   = RES_LEN_D[t];
  const int Lp1 = L + 1;
  const int Mh  = (Lp1 + 1) >> 1;       // number of m-slot pairs

  __shared__ float w_lds[NSLOT * LMAX * DV];       // [slot m][l][v]
  __shared__ float diff_lds[BATCH * LMAX * DPAD];  // [b][l][x y z x y z -]

  // ---- start_i = sum of lens of residues < i ----
  int* red = (int*)w_lds;
  {
    int s = 0;
    int base = tid * 8;
    #pragma unroll
    for (int k = 0; k < 8; ++k) {
      int r = base + k;
      if (r < i) s += RES_LEN_D[seq[r]];
    }
    red[tid] = s;
  }
  __syncthreads();
  #pragma unroll
  for (int off = 128; off > 0; off >>= 1) {
    if (tid < off) red[tid] += red[tid + off];
    __syncthreads();
  }
  const int start = red[0];
  __syncthreads();   // release the alias before W staging

  // ---- stage diffs replicated: [b][l] -> (x,y,z,x,y,z) ----
  if (tid < BATCH * LMAX) {
    int b = tid / LMAX;
    int l = tid - b * LMAX;
    float dx = 0.f, dy = 0.f, dz = 0.f;
    if (l < L) {
      const float* pa = pos_atm + ((size_t)b * atoms + (size_t)(start + l)) * 3;
      const float* pm = pos_amn + ((size_t)b * N_RES + i) * 3;
      dx = pa[0] - pm[0];
      dy = pa[1] - pm[1];
      dz = pa[2] - pm[2];
    }
    float* dd = diff_lds + tid * DPAD;
    dd[0] = dx; dd[1] = dy; dd[2] = dz;
    dd[3] = dx; dd[4] = dy; dd[5] = dz;
  }

  // ---- stage W_atm[t] transposed (m,v,l)->[m][l][v], m < L ----
  {
    const float* Wt = W_atm + (size_t)t * (LMAX * DV * LMAX);
    const int total = L * DV * LMAX;
    for (int g = tid; g < total; g += 256) {
      int m = g / (DV * LMAX);
      int r = g - m * (DV * LMAX);
      int v = r / LMAX;
      int l = r - v * LMAX;
      w_lds[(m * LMAX + l) * DV + v] = Wt[g];
    }
    // ---- stage W_amn[t] (o,l)->[slot L][l][o] ----
    const float* Wa = W_amn + (size_t)t * (DV * LMAX);
    for (int g = tid; g < DV * LMAX; g += 256) {
      int o = g / LMAX;
      int l = g - o * LMAX;
      w_lds[(L * LMAX + l) * DV + o] = Wa[g];
    }
  }
  __syncthreads();

  // ---- compute: task = (lam: float4 within 192-float row) x (mh: m-pair) x (bh: b-pair) ----
  const int ntasks = 48 * 8 * Mh;

  for (int task = tid; task < ntasks; task += 256) {
    int lam = task % 48;          // float4 index within row
    int rg  = task / 48;
    int mh  = rg % Mh;
    int bh  = rg / Mh;
    int m0  = mh * 2, m1 = m0 + 1;
    int b0  = bh * 2, b1 = b0 + 1;

    int f0 = lam * 4;             // first float index of this float4
    int va = f0 / 3;              // first v channel
    int r  = f0 - va * 3;         // rotation
    int th = 3 - r;               // e < th -> w[va], else w[va+1]

    const float* w0 = w_lds + (m0 * LMAX) * DV + va;
    const float* w1 = w_lds + (m1 * LMAX) * DV + va;
    const float* p0 = diff_lds + (b0 * LMAX) * DPAD + r;
    const float* p1 = diff_lds + (b1 * LMAX) * DPAD + r;

    float a00[4] = {0.f,0.f,0.f,0.f};
    float a01[4] = {0.f,0.f,0.f,0.f};
    float a10[4] = {0.f,0.f,0.f,0.f};
    float a11[4] = {0.f,0.f,0.f,0.f};

    for (int l = 0; l < L; ++l) {
      float wa0 = w0[l * DV], wb0 = w0[l * DV + 1];
      float wa1 = w1[l * DV], wb1 = w1[l * DV + 1];
      float r0[4], r1[4];
      #pragma unroll
      for (int e = 0; e < 4; ++e) { r0[e] = p0[l * DPAD + e]; r1[e] = p1[l * DPAD + e]; }
      #pragma unroll
      for (int e = 0; e < 4; ++e) {
        float ws0 = (e < th) ? wa0 : wb0;
        float ws1 = (e < th) ? wa1 : wb1;
        a00[e] += ws0 * r0[e];
        a01[e] += ws0 * r1[e];
        a10[e] += ws1 * r0[e];
        a11[e] += ws1 * r1[e];
      }
    }

    // ---- stores: lane-contiguous float4s ----
    {
      float* dst;
      if (m0 < L) dst = out_atm + ((size_t)b0 * atoms + (size_t)(start + m0)) * 192 + f0;
      else        dst = out_amn + ((size_t)b0 * N_RES + i) * 192 + f0;
      *(float4*)dst = make_float4(a00[0], a00[1], a00[2], a00[3]);
      if (m0 < L) dst = out_atm + ((size_t)b1 * atoms + (size_t)(start + m0)) * 192 + f0;
      else        dst = out_amn + ((size_t)b1 * N_RES + i) * 192 + f0;
      *(float4*)dst = make_float4(a01[0], a01[1], a01[2], a01[3]);
    }
    if (m1 <= L) {
      float* dst;
      if (m1 < L) dst = out_atm + ((size_t)b0 * atoms + (size_t)(start + m1)) * 192 + f0;
      else        dst = out_amn + ((size_t)b0 * N_RES + i) * 192 + f0;
      *(float4*)dst = make_float4(a10[0], a10[1], a10[2], a10[3]);
      if (m1 < L) dst = out_atm + ((size_t)b1 * atoms + (size_t)(start + m1)) * 192 + f0;
      else        dst = out_amn + ((size_t)b1 * N_RES + i) * 192 + f0;
      *(float4*)dst = make_float4(a11[0], a11[1], a11[2], a11[3]);
    }
  }
}

extern "C" void kernel_launch(void* const* d_in, const int* in_sizes, int n_in,
                              void* d_out, int out_size, void* d_ws, size_t ws_size,
                              hipStream_t stream) {
  const float* pos_atm = (const float*)d_in[0];
  const float* pos_amn = (const float*)d_in[1];
  const float* W_amn   = (const float*)d_in[2];
  const float* W_atm   = (const float*)d_in[3];
  const int*   seq     = (const int*)d_in[4];

  const int atoms = in_sizes[0] / (BATCH * 3);   // 15036
  float* out_atm = (float*)d_out;
  float* out_amn = out_atm + (size_t)BATCH * atoms * DV * 3;

  posmix_kernel<<<N_RES, 256, 0, stream>>>(pos_atm, pos_amn, W_amn, W_atm, seq,
                                           out_atm, out_amn, atoms);
}